// Round 5
// baseline (175.030 us; speedup 1.0000x reference)
//
#include <hip/hip_runtime.h>
#include <math.h>

#define EDIM 128
#define NHEAD 16
#define HDIM 8
#define SEQ 2048
#define BATCH 4
#define NROW (BATCH*SEQ)            // 8192
// -scale*log2(e): folded into Q at projection time so sigmoid = rcp(1+exp2(dot))
#define QNEG (-0.35355339059327373f * 1.4426950408889634f)

#if __has_builtin(__builtin_amdgcn_exp2f)
#define EXP2F(x) __builtin_amdgcn_exp2f(x)
#else
#define EXP2F(x) exp2f(x)
#endif
#define RCPF(x) __builtin_amdgcn_rcpf(x)

typedef __attribute__((ext_vector_type(8))) short short8v;
typedef __attribute__((ext_vector_type(4))) short short4v;
typedef __attribute__((ext_vector_type(4))) float float4v;

union U16x8 { uint4 u; short8v s; };
union U16x4 { uint2 u; short4v s; };

#if __has_builtin(__builtin_amdgcn_mfma_f32_16x16x16bf16_1k)
#define MFMA_PV(a,b,c) __builtin_amdgcn_mfma_f32_16x16x16bf16_1k(a,b,c,0,0,0)
#else
static __device__ __forceinline__ float4v mfma_pv_asm(short4v a, short4v b, float4v c) {
  float4v d;
  asm("v_mfma_f32_16x16x16_bf16 %0, %1, %2, %3" : "=v"(d) : "v"(a), "v"(b), "v"(c));
  return d;
}
#define MFMA_PV(a,b,c) mfma_pv_asm(a,b,c)
#endif

// pack two floats to bf16x2, round-to-nearest-even (values finite)
__device__ __forceinline__ unsigned pk_bf16(float a, float b) {
  unsigned ua = __float_as_uint(a), ub = __float_as_uint(b);
  unsigned lo = (ua + 0x7fffu + ((ua >> 16) & 1u)) >> 16;
  unsigned hi = (ub + 0x7fffu + ((ub >> 16) & 1u)) & 0xffff0000u;
  return lo | hi;
}

// ---------------------------------------------------------------------------
// Transpose the 4 weight matrices W[j][i] -> WT[i][j].  (Restored: direct-W
// reads in the GEMM put lanes at 2KB stride = 32 lines/instr, uncoalesced —
// measured +24us. WT reads are 16B-stride coalesced.)
// ---------------------------------------------------------------------------
__global__ __launch_bounds__(256)
void transpose4_kernel(const float* __restrict__ W0, const float* __restrict__ W1,
                       const float* __restrict__ W2, const float* __restrict__ W3,
                       float* __restrict__ WT)
{
  const float* W = (blockIdx.y == 0) ? W0 : (blockIdx.y == 1) ? W1
                 : (blockIdx.y == 2) ? W2 : W3;
  float* out = WT + blockIdx.y * EDIM * EDIM;
  const int i0 = blockIdx.x * 16;
  #pragma unroll
  for (int it = 0; it < 8; ++it) {
    int f = threadIdx.x + it * 256;
    int i = i0 + (f >> 7);
    int j = f & 127;
    out[i * EDIM + j] = W[j * EDIM + i];
  }
}

// ---------------------------------------------------------------------------
// out = X @ W^T + b with pre-transposed WT. 8 rows x 128 cols per block.
// 8-row tiles (was 32): grid qkv 3072 / oproj 1024 blocks -> 12 / 4
// blocks/CU instead of 3 / 1. Measured: qkv was 50.7us at 17% VALUBusy,
// 24.6% occupancy — pure latency exposure from grid starvation.
// MODE 0: Q scaled by QNEG -> bf16 [bh][s][8]
// MODE 1: K -> bf16 [bh][s][8]  (coalesced uint2 stores)
// MODE 2: V -> bf16 TILE-BLOCKED TRANSPOSE Vt[bh][t=s>>4][d][si=s&15]
//         via LDS bounce; an 8-row block fills half a 16-s tile (si_off 0/8)
// MODE 3: fp32 row-major [rows][128] (final output)
// ---------------------------------------------------------------------------
template<int MODE>
__device__ __forceinline__
void proj_body(const float* __restrict__ X, const float* __restrict__ WT,
               const float* __restrict__ bias, void* __restrict__ out)
{
  __shared__ float xs[8][EDIM];                   // 4 KB (reused as vs, MODE 2)
  const int tid = threadIdx.x;
  const int row0 = blockIdx.x * 8;

  // stage 8 rows of X: 256 threads x 1 float4 = 4 KB
  ((float4*)&xs[0][0])[tid] = ((const float4*)(X + row0 * EDIM))[tid];
  __syncthreads();

  const int tc = tid & 31;
  const int tr = tid >> 5;                        // 0..7, ONE row each
  const int col0 = tc * 4;

  float a0 = 0.f, a1 = 0.f, a2 = 0.f, a3 = 0.f;

  #pragma unroll 2
  for (int ib = 0; ib < EDIM / 4; ++ib) {
    const float4 w0 = *(const float4*)(WT + (4 * ib + 0) * EDIM + col0);
    const float4 w1 = *(const float4*)(WT + (4 * ib + 1) * EDIM + col0);
    const float4 w2 = *(const float4*)(WT + (4 * ib + 2) * EDIM + col0);
    const float4 w3 = *(const float4*)(WT + (4 * ib + 3) * EDIM + col0);
    const float4 x4 = *(const float4*)(&xs[tr][ib * 4]);   // b128 broadcast
    a0 += x4.x * w0.x + x4.y * w1.x + x4.z * w2.x + x4.w * w3.x;
    a1 += x4.x * w0.y + x4.y * w1.y + x4.z * w2.y + x4.w * w3.y;
    a2 += x4.x * w0.z + x4.y * w1.z + x4.z * w2.z + x4.w * w3.z;
    a3 += x4.x * w0.w + x4.y * w1.w + x4.z * w2.w + x4.w * w3.w;
  }

  const float4 b4 = *(const float4*)(bias + col0);
  const float4 o = make_float4(a0 + b4.x, a1 + b4.y, a2 + b4.z, a3 + b4.w);

  if (MODE == 2) {
    // --- V tile-blocked transpose: o -> bf16 in LDS [s(8)][col(128)], then
    // transposed readout of this 8-s half-tile to Vt[bh][tg][dd][si]. ---
    __syncthreads();                              // all lanes done reading xs
    unsigned short* vs = (unsigned short*)&xs[0][0];   // [8][128] u16 = 2 KB
    uint2 p;
    p.x = pk_bf16(o.x, o.y);
    p.y = pk_bf16(o.z, o.w);
    *(uint2*)(vs + tr * EDIM + col0) = p;
    __syncthreads();
    if (tid < 128) {
      const unsigned short* sp = vs + tid;        // column = h*8+d = tid
      unsigned wb[4];
      #pragma unroll
      for (int i = 0; i < 4; ++i)
        wb[i] = (unsigned)sp[(2 * i) * EDIM] | ((unsigned)sp[(2 * i + 1) * EDIM] << 16);
      const int b_ = row0 >> 11, s0 = row0 & (SEQ - 1);
      const int h = tid >> 3, dd = tid & 7;
      const int bh = b_ * NHEAD + h;
      const int tg = s0 >> 4;                     // global k-tile index
      const int si = s0 & 15;                     // 0 or 8: which half-tile
      unsigned short* dp = (unsigned short*)out
          + (size_t)bh * (SEQ * HDIM) + tg * 128 + dd * 16 + si;
      *(uint4*)dp = make_uint4(wb[0], wb[1], wb[2], wb[3]);
    }
    return;
  }

  if (MODE == 3) {
    *(float4*)((float*)out + (size_t)(row0 + tr) * EDIM + col0) = o;
  } else {
    const int grow = row0 + tr;
    const int b = grow >> 11, s = grow & (SEQ - 1);
    const int h = col0 >> 3, d0 = col0 & 7;       // d0 in {0,4}
    const size_t bhs = (size_t)(b * NHEAD + h) * SEQ + s;
    uint2 p;
    if (MODE == 0) {
      p.x = pk_bf16(o.x * QNEG, o.y * QNEG);
      p.y = pk_bf16(o.z * QNEG, o.w * QNEG);
    } else {
      p.x = pk_bf16(o.x, o.y);
      p.y = pk_bf16(o.z, o.w);
    }
    *(uint2*)((unsigned*)out + bhs * 4 + (d0 >> 1)) = p;
  }
}

__global__ __launch_bounds__(256)
void qkv_kernel(const float* __restrict__ X, const float* __restrict__ WT,
                const float* __restrict__ bq, const float* __restrict__ bk,
                const float* __restrict__ bv,
                unsigned* __restrict__ qb, unsigned* __restrict__ kb,
                unsigned* __restrict__ vb)
{
  const int m = blockIdx.y;
  const float* wt = WT + m * EDIM * EDIM;
  if (m == 0)      proj_body<0>(X, wt, bq, (void*)qb);
  else if (m == 1) proj_body<1>(X, wt, bk, (void*)kb);
  else             proj_body<2>(X, wt, bv, (void*)vb);
}

__global__ __launch_bounds__(256)
void oproj_kernel(const float* __restrict__ A, const float* __restrict__ WTo,
                  const float* __restrict__ bo, float* __restrict__ out)
{
  proj_body<3>(A, WTo, bo, (void*)out);
}

// ---------------------------------------------------------------------------
// One 16q x 16k MFMA step.  (round-0 verified sigmoid path)
// S^T = mfma_16x16x32_bf16(A=K-rows, B=Q-frag) -> C[key][q]. Sigmoid
// elementwise; C-register reinterpreted as A-operand of mfma_16x16x16 gives
// the UN-transposed P, so out[q][d] = mfma(A=P, B=V-frag, acc). V-frag col 8
// is forced to 1.0 so acc col 8 accumulates the denominator.
// ---------------------------------------------------------------------------
template<bool DIAG>
__device__ __forceinline__
float4v attn_step(short8v kf, short8v qf, short4v vf, float4v acc,
                  int laneq, int quad)
{
  const float4v z = {0.f, 0.f, 0.f, 0.f};
  float4v st = __builtin_amdgcn_mfma_f32_16x16x32_bf16(kf, qf, z, 0, 0, 0);
  unsigned rb[4];
  #pragma unroll
  for (int r = 0; r < 4; ++r) {
    float s = RCPF(1.f + EXP2F(st[r]));           // Q carries -scale*log2e
    if (DIAG) s = (4 * quad + r <= laneq) ? s : 0.f;  // exact: sigma(-1e9)==0
    rb[r] = __float_as_uint(s) + 0x8000u;         // round-half-up to bf16
  }
  U16x4 p;
  p.u.x = __builtin_amdgcn_perm(rb[1], rb[0], 0x07060302u);
  p.u.y = __builtin_amdgcn_perm(rb[3], rb[2], 0x07060302u);
  return MFMA_PV(p.s, vf, acc);                   // A = P[q][k], B = V[k][d]
}

// V-frag loader from tile-blocked Vt[bh][t][d][si]: ONE dwordx2 from a
// contiguous 256B tile block. lanes laneq==8 -> bf16 1.0 (denominator col).
__device__ __forceinline__
short4v load_vfrag(const unsigned short* __restrict__ Vtbh, int t,
                   int quad, int d, bool is8)
{
  const unsigned short* p = Vtbh + t * 128 + d * 16 + 4 * quad;
  const uint2 v = *(const uint2*)p;
  U16x4 vf;
  vf.u.x = is8 ? 0x3F803F80u : v.x;
  vf.u.y = is8 ? 0x3F803F80u : v.y;
  return vf.s;
}

// epilogue: den = acc col 8; normalize and store rows of tile T
__device__ __forceinline__
void epilogue(float4v acc, int T, int bh, int laneq, int quad,
              float* __restrict__ out)
{
  const int b_ = bh >> 4, h = bh & 15;
  const int pidx = (quad * 16 + 8) << 2;          // lane holding col 8
  #pragma unroll
  for (int r = 0; r < 4; ++r) {
    const float den = __int_as_float(
        __builtin_amdgcn_ds_bpermute(pidx, __float_as_int(acc[r])));
    const float val = acc[r] * RCPF(den);         // den > 0
    const int row = 16 * T + 4 * quad + r;
    if (laneq < 8)
      out[(size_t)(b_ * SEQ + row) * EDIM + h * HDIM + laneq] = val;
  }
}

// ---------------------------------------------------------------------------
// Causal sigmoid-attention v11: v8 split-K x2 fold-pair schedule, with
// dwordx2 V-frag loads from tile-blocked Vt (contiguous 256B per tile).
// blockIdx low 6 bits = bh -> XCD = bh%8 (L2 locality).
// ---------------------------------------------------------------------------
__global__ __launch_bounds__(128, 8)
void attn_kernel(const unsigned* __restrict__ Qb, const unsigned* __restrict__ Kb,
                 const unsigned* __restrict__ Vb, float* __restrict__ out)
{
  __shared__ float cmb[2][64][4];                 // 2 KB

  const int bh    = blockIdx.x & 63;
  const int g     = blockIdx.x >> 6;              // 0..63
  const int w     = threadIdx.x >> 6;
  const int lane  = threadIdx.x & 63;
  const int laneq = lane & 15;
  const int quad  = lane >> 4;
  const int L = g, H = 127 - g;
  const int mL = (L + 1) >> 1, mH = (H + 1) >> 1;
  const int d   = laneq & 7;
  const bool is8 = (laneq == 8);

  const uint4* Kg = (const uint4*)Kb + (size_t)bh * 2048;
  const uint4* Qg = (const uint4*)Qb + (size_t)bh * 2048;
  const unsigned short* Vtbh = (const unsigned short*)Vb + (size_t)bh * SEQ * HDIM;

  // Q B-frags: lanes<16 hold the 8-dim row in quad 0 (k=0..7); zero others
  U16x8 qfl, qfh;
  {
    const uint4 rl = Qg[16 * L + laneq];
    const uint4 rh = Qg[16 * H + laneq];
    qfl.u = (lane < 16) ? rl : make_uint4(0u, 0u, 0u, 0u);
    qfh.u = (lane < 16) ? rh : make_uint4(0u, 0u, 0u, 0u);
  }

  float4v accL = {0.f, 0.f, 0.f, 0.f};
  float4v accH = {0.f, 0.f, 0.f, 0.f};

  if (w == 0) {
    // k-tiles [0,mL) dual (L+H), [mL,mH) H-only; no diags; prefetch 1 deep
    U16x8 kf; kf.u = Kg[laneq];
    short4v vf = load_vfrag(Vtbh, 0, quad, d, is8);
    #pragma unroll 2
    for (int t = 0; t < mH; ++t) {
      U16x8 kn; kn.u = Kg[16 * (t + 1) + laneq];  // t+1 <= mH <= 64: in-bounds
      short4v vn = load_vfrag(Vtbh, t + 1, quad, d, is8);
      if (t < mL) accL = attn_step<false>(kf.s, qfl.s, vf, accL, laneq, quad);
      accH = attn_step<false>(kf.s, qfh.s, vf, accH, laneq, quad);
      kf = kn; vf = vn;
    }
  } else {
    // L segment: [mL, L], diag at L
    U16x8 kf; kf.u = Kg[16 * mL + laneq];
    short4v vf = load_vfrag(Vtbh, mL, quad, d, is8);
    #pragma unroll 2
    for (int t = mL; t < L; ++t) {
      U16x8 kn; kn.u = Kg[16 * (t + 1) + laneq];
      short4v vn = load_vfrag(Vtbh, t + 1, quad, d, is8);
      accL = attn_step<false>(kf.s, qfl.s, vf, accL, laneq, quad);
      kf = kn; vf = vn;
    }
    accL = attn_step<true>(kf.s, qfl.s, vf, accL, laneq, quad);
    // H segment: [mH, H], diag at H
    kf.u = Kg[16 * mH + laneq];
    vf = load_vfrag(Vtbh, mH, quad, d, is8);
    #pragma unroll 2
    for (int t = mH; t < H; ++t) {
      U16x8 kn; kn.u = Kg[16 * (t + 1) + laneq];  // t+1 <= H = 127: in-bounds
      short4v vn = load_vfrag(Vtbh, t + 1, quad, d, is8);
      accH = attn_step<false>(kf.s, qfh.s, vf, accH, laneq, quad);
      kf = kn; vf = vn;
    }
    accH = attn_step<true>(kf.s, qfh.s, vf, accH, laneq, quad);

    *(float4*)&cmb[0][lane][0] = make_float4(accL[0], accL[1], accL[2], accL[3]);
    *(float4*)&cmb[1][lane][0] = make_float4(accH[0], accH[1], accH[2], accH[3]);
  }
  __syncthreads();

  if (w == 0) {
    const float4 pL = *(const float4*)&cmb[0][lane][0];
    const float4 pH = *(const float4*)&cmb[1][lane][0];
    accL[0] += pL.x; accL[1] += pL.y; accL[2] += pL.z; accL[3] += pL.w;
    accH[0] += pH.x; accH[1] += pH.y; accH[2] += pH.z; accH[3] += pH.w;
    epilogue(accL, L, bh, laneq, quad, out);
    epilogue(accH, H, bh, laneq, quad, out);
  }
}

// ---------------------------------------------------------------------------
extern "C" void kernel_launch(void* const* d_in, const int* in_sizes, int n_in,
                              void* d_out, int out_size, void* d_ws, size_t ws_size,
                              hipStream_t stream)
{
  const float* x  = (const float*)d_in[0];
  const float* Wq = (const float*)d_in[1];
  const float* bq = (const float*)d_in[2];
  const float* Wk = (const float*)d_in[3];
  const float* bk = (const float*)d_in[4];
  const float* Wv = (const float*)d_in[5];
  const float* bv = (const float*)d_in[6];
  const float* Wo = (const float*)d_in[7];
  const float* bo = (const float*)d_in[8];

  float* ws = (float*)d_ws;
  // layout: WT 65536 f | attn 1048576 f | Qb, Kb, Vt 524288 dwords each
  float*    WT   = ws;
  float*    attn = ws + 65536;
  unsigned* Qb   = (unsigned*)(ws + 65536 + 1048576);
  unsigned* Kb   = Qb + (size_t)524288;
  unsigned* Vb   = Kb + (size_t)524288;

  transpose4_kernel<<<dim3(8, 4), 256, 0, stream>>>(Wq, Wk, Wv, Wo, WT);
  qkv_kernel<<<dim3(NROW / 8, 3), 256, 0, stream>>>(x, WT, bq, bk, bv, Qb, Kb, Vb);
  attn_kernel<<<dim3(4096), 128, 0, stream>>>(Qb, Kb, Vb, attn);
  oproj_kernel<<<dim3(NROW / 8), 256, 0, stream>>>(attn, WT + 3 * EDIM * EDIM, bo,
                                                   (float*)d_out);
}

// Round 6
// 121.970 us; speedup vs baseline: 1.4350x; 1.4350x over previous
//
#include <hip/hip_runtime.h>
#include <math.h>

#define EDIM 128
#define NHEAD 16
#define HDIM 8
#define SEQ 2048
#define BATCH 4
#define NROW (BATCH*SEQ)            // 8192
// -scale*log2(e): folded into Q at projection time so sigmoid = rcp(1+exp2(dot))
#define QNEG (-0.35355339059327373f * 1.4426950408889634f)

#if __has_builtin(__builtin_amdgcn_exp2f)
#define EXP2F(x) __builtin_amdgcn_exp2f(x)
#else
#define EXP2F(x) exp2f(x)
#endif
#define RCPF(x) __builtin_amdgcn_rcpf(x)

typedef __attribute__((ext_vector_type(8))) short short8v;
typedef __attribute__((ext_vector_type(4))) short short4v;
typedef __attribute__((ext_vector_type(4))) float float4v;

union U16x8 { uint4 u; short8v s; };
union U16x4 { uint2 u; short4v s; };

#if __has_builtin(__builtin_amdgcn_mfma_f32_16x16x16bf16_1k)
#define MFMA_PV(a,b,c) __builtin_amdgcn_mfma_f32_16x16x16bf16_1k(a,b,c,0,0,0)
#else
static __device__ __forceinline__ float4v mfma_pv_asm(short4v a, short4v b, float4v c) {
  float4v d;
  asm("v_mfma_f32_16x16x16_bf16 %0, %1, %2, %3" : "=v"(d) : "v"(a), "v"(b), "v"(c));
  return d;
}
#define MFMA_PV(a,b,c) mfma_pv_asm(a,b,c)
#endif

// pack two floats to bf16x2, round-to-nearest-even-ish (values finite)
__device__ __forceinline__ unsigned pk_bf16(float a, float b) {
  unsigned ua = __float_as_uint(a), ub = __float_as_uint(b);
  unsigned lo = (ua + 0x7fffu + ((ua >> 16) & 1u)) >> 16;
  unsigned hi = (ub + 0x7fffu + ((ub >> 16) & 1u)) & 0xffff0000u;
  return lo | hi;
}

// ---------------------------------------------------------------------------
// Cast the 4 weight matrices to bf16, UN-transposed row-major [4][128][128].
// The MFMA B-operand wants B[k][n] = W[n][k]: lane l reads 8 CONTIGUOUS
// elements of W row (n0+l&15) — the transpose falls out of the fragment
// layout, so no transpose pass is needed at all.
// ---------------------------------------------------------------------------
__global__ __launch_bounds__(256)
void cast4_kernel(const float* __restrict__ W0, const float* __restrict__ W1,
                  const float* __restrict__ W2, const float* __restrict__ W3,
                  unsigned short* __restrict__ Wb)
{
  const float* W = (blockIdx.y == 0) ? W0 : (blockIdx.y == 1) ? W1
                 : (blockIdx.y == 2) ? W2 : W3;
  unsigned short* o = Wb + (size_t)blockIdx.y * (EDIM * EDIM);
  const int i = (blockIdx.x * 256 + threadIdx.x) * 4;
  const float4 f = *(const float4*)(W + i);
  uint2 p;
  p.x = pk_bf16(f.x, f.y);
  p.y = pk_bf16(f.z, f.w);
  *(uint2*)(o + i) = p;
}

// ---------------------------------------------------------------------------
// MFMA projection: out = X @ W^T + b.  16 rows x 128 cols per 256-thr block
// (4 waves; wave wv owns cols [32wv, 32wv+32) as two 16-col MFMA tiles).
// Per wave: 4 ds_read_b128 A-frags + 8 global 16B B-frags + 8 MFMA.
// Fragment layouts (verified by this codebase's attn kernel + guide m89):
//   A lane l: A[m=l&15][k=(l>>4)*8+j]   B lane l: B[k=(l>>4)*8+j][n=l&15]
//   D lane l: D[m=(l>>4)*4+r][n=l&15]
// X tile staged fp32->bf16 into XOR-swizzled LDS (addr ^= (row&7)<<4, G4).
// MODE 0: Q scaled by QNEG -> bf16 [bh][s][8]
// MODE 1: K -> bf16 [bh][s][8]
// MODE 2: V -> bf16 tile-blocked transpose Vt[bh][t=s>>4][d][si=s&15]
// MODE 3: fp32 row-major [rows][128] (final output)
// ---------------------------------------------------------------------------
template<int MODE>
__device__ __forceinline__
void proj_mfma(const float* __restrict__ X, const unsigned short* __restrict__ Wb,
               const float* __restrict__ bias, void* __restrict__ out)
{
  __shared__ unsigned short xs[16 * EDIM];        // 4 KB, XOR-swizzled rows
  const int tid = threadIdx.x;
  const int row0 = blockIdx.x * 16;

  // stage 16 rows of X as bf16: thread (r = tid>>4, chunk c16 = tid&15)
  // loads 8 fp32 (32B, coalesced 512B per 16 threads) -> 16B bf16 chunk.
  {
    const int r = tid >> 4, c16 = tid & 15;
    const float4* src = (const float4*)(X + (size_t)(row0 + r) * EDIM + c16 * 8);
    const float4 f0 = src[0], f1 = src[1];
    uint4 v;
    v.x = pk_bf16(f0.x, f0.y); v.y = pk_bf16(f0.z, f0.w);
    v.z = pk_bf16(f1.x, f1.y); v.w = pk_bf16(f1.z, f1.w);
    const unsigned addr = (unsigned)(r * 256 + c16 * 16) ^ (unsigned)((r & 7) << 4);
    *(uint4*)((char*)xs + addr) = v;
  }
  __syncthreads();

  const int lane = tid & 63, wv = tid >> 6;
  const int lq = lane & 15, qd = lane >> 4;
  const int n0 = wv * 32;

  // A-frags: lane reads 16B of row lq at k-offset kk*32+qd*8 (swizzled)
  short8v a[4];
  #pragma unroll
  for (int kk = 0; kk < 4; ++kk) {
    const unsigned addr =
        (unsigned)(lq * 256 + kk * 64 + qd * 16) ^ (unsigned)((lq & 7) << 4);
    a[kk] = *(const short8v*)((const char*)xs + addr);
  }

  // B-frags from bf16 W rows (contiguous 16B) + MFMA accumulate
  float4v D0 = {0.f, 0.f, 0.f, 0.f}, D1 = {0.f, 0.f, 0.f, 0.f};
  const unsigned short* wr0 = Wb + (size_t)(n0 + lq) * EDIM + qd * 8;
  #pragma unroll
  for (int kk = 0; kk < 4; ++kk) {
    U16x8 b0, b1;
    b0.u = *(const uint4*)(wr0 + kk * 32);
    b1.u = *(const uint4*)(wr0 + 16 * EDIM + kk * 32);
    D0 = __builtin_amdgcn_mfma_f32_16x16x32_bf16(a[kk], b0.s, D0, 0, 0, 0);
    D1 = __builtin_amdgcn_mfma_f32_16x16x32_bf16(a[kk], b1.s, D1, 0, 0, 0);
  }

  const int nA = n0 + lq, nB = nA + 16;
  const float bzA = bias[nA], bzB = bias[nB];

  if (MODE == 3) {
    float* of = (float*)out + (size_t)(row0 + qd * 4) * EDIM + nA;
    #pragma unroll
    for (int r = 0; r < 4; ++r) {
      of[r * EDIM]      = D0[r] + bzA;
      of[r * EDIM + 16] = D1[r] + bzB;
    }
    return;
  }

  if (MODE == 2) {
    // Vt[bh][tg][d][si]: block = exactly one 16-s tile (row0 is 16-aligned);
    // si = qd*4 + r -> each lane stores one uint2 (4 consecutive si) per tile.
    const int b_ = row0 >> 11, srel = row0 & (SEQ - 1);
    const int tg = srel >> 4;
    unsigned short* oU = (unsigned short*)out;
    {
      const int bh = b_ * NHEAD + (nA >> 3), dv = nA & 7;
      uint2 p;
      p.x = pk_bf16(D0[0] + bzA, D0[1] + bzA);
      p.y = pk_bf16(D0[2] + bzA, D0[3] + bzA);
      *(uint2*)(oU + (size_t)bh * (SEQ * HDIM) + tg * 128 + dv * 16 + qd * 4) = p;
    }
    {
      const int bh = b_ * NHEAD + (nB >> 3), dv = nB & 7;
      uint2 p;
      p.x = pk_bf16(D1[0] + bzB, D1[1] + bzB);
      p.y = pk_bf16(D1[2] + bzB, D1[3] + bzB);
      *(uint2*)(oU + (size_t)bh * (SEQ * HDIM) + tg * 128 + dv * 16 + qd * 4) = p;
    }
    return;
  }

  // MODE 0/1: [bh][s][8] u16 elements; lane col fixed -> u16 scatter, rows r
  {
    const int b_ = row0 >> 11;
    const int srel = (row0 & (SEQ - 1)) + qd * 4;
    unsigned short* oU = (unsigned short*)out;
    const int bhA = b_ * NHEAD + (nA >> 3), dvA = nA & 7;
    const int bhB = bhA + 2;                      // nB = nA+16 -> h+2, same d
    unsigned short* pA = oU + ((size_t)bhA * SEQ + srel) * 8 + dvA;
    unsigned short* pB = oU + ((size_t)bhB * SEQ + srel) * 8 + dvA;
    #pragma unroll
    for (int r = 0; r < 4; ++r) {
      float vA = D0[r] + bzA, vB = D1[r] + bzB;
      if (MODE == 0) { vA *= QNEG; vB *= QNEG; }
      pA[r * 8] = (unsigned short)pk_bf16(vA, 0.f);
      pB[r * 8] = (unsigned short)pk_bf16(vB, 0.f);
    }
    return;
  }
}

__global__ __launch_bounds__(256)
void qkv_kernel(const float* __restrict__ X, const unsigned short* __restrict__ Wb,
                const float* __restrict__ bq, const float* __restrict__ bk,
                const float* __restrict__ bv,
                unsigned* __restrict__ qb, unsigned* __restrict__ kb,
                unsigned* __restrict__ vb)
{
  const int m = blockIdx.y;
  const unsigned short* wb = Wb + (size_t)m * EDIM * EDIM;
  if (m == 0)      proj_mfma<0>(X, wb, bq, (void*)qb);
  else if (m == 1) proj_mfma<1>(X, wb, bk, (void*)kb);
  else             proj_mfma<2>(X, wb, bv, (void*)vb);
}

__global__ __launch_bounds__(256)
void oproj_kernel(const float* __restrict__ A, const unsigned short* __restrict__ Wbo,
                  const float* __restrict__ bo, float* __restrict__ out)
{
  proj_mfma<3>(A, Wbo, bo, (void*)out);
}

// ---------------------------------------------------------------------------
// One 16q x 16k MFMA step.  (round-0 verified sigmoid path)
// S^T = mfma_16x16x32_bf16(A=K-rows, B=Q-frag) -> C[key][q]. Sigmoid
// elementwise; C-register reinterpreted as A-operand of mfma_16x16x16 gives
// the UN-transposed P, so out[q][d] = mfma(A=P, B=V-frag, acc). V-frag col 8
// is forced to 1.0 so acc col 8 accumulates the denominator.
// ---------------------------------------------------------------------------
template<bool DIAG>
__device__ __forceinline__
float4v attn_step(short8v kf, short8v qf, short4v vf, float4v acc,
                  int laneq, int quad)
{
  const float4v z = {0.f, 0.f, 0.f, 0.f};
  float4v st = __builtin_amdgcn_mfma_f32_16x16x32_bf16(kf, qf, z, 0, 0, 0);
  unsigned rb[4];
  #pragma unroll
  for (int r = 0; r < 4; ++r) {
    float s = RCPF(1.f + EXP2F(st[r]));           // Q carries -scale*log2e
    if (DIAG) s = (4 * quad + r <= laneq) ? s : 0.f;  // exact: sigma(-1e9)==0
    rb[r] = __float_as_uint(s) + 0x8000u;         // round-half-up to bf16
  }
  U16x4 p;
  p.u.x = __builtin_amdgcn_perm(rb[1], rb[0], 0x07060302u);
  p.u.y = __builtin_amdgcn_perm(rb[3], rb[2], 0x07060302u);
  return MFMA_PV(p.s, vf, acc);                   // A = P[q][k], B = V[k][d]
}

// V-frag loader from tile-blocked Vt[bh][t][d][si]: ONE dwordx2 from a
// contiguous 256B tile block. lanes laneq==8 -> bf16 1.0 (denominator col).
__device__ __forceinline__
short4v load_vfrag(const unsigned short* __restrict__ Vtbh, int t,
                   int quad, int d, bool is8)
{
  const unsigned short* p = Vtbh + t * 128 + d * 16 + 4 * quad;
  const uint2 v = *(const uint2*)p;
  U16x4 vf;
  vf.u.x = is8 ? 0x3F803F80u : v.x;
  vf.u.y = is8 ? 0x3F803F80u : v.y;
  return vf.s;
}

// epilogue: den = acc col 8; normalize and store rows of tile T
__device__ __forceinline__
void epilogue(float4v acc, int T, int bh, int laneq, int quad,
              float* __restrict__ out)
{
  const int b_ = bh >> 4, h = bh & 15;
  const int pidx = (quad * 16 + 8) << 2;          // lane holding col 8
  #pragma unroll
  for (int r = 0; r < 4; ++r) {
    const float den = __int_as_float(
        __builtin_amdgcn_ds_bpermute(pidx, __float_as_int(acc[r])));
    const float val = acc[r] * RCPF(den);         // den > 0
    const int row = 16 * T + 4 * quad + r;
    if (laneq < 8)
      out[(size_t)(b_ * SEQ + row) * EDIM + h * HDIM + laneq] = val;
  }
}

// ---------------------------------------------------------------------------
// Causal sigmoid-attention v11: v8 split-K x2 fold-pair schedule, with
// dwordx2 V-frag loads from tile-blocked Vt (contiguous 256B per tile).
// blockIdx low 6 bits = bh -> XCD = bh%8 (L2 locality).
// ---------------------------------------------------------------------------
__global__ __launch_bounds__(128, 8)
void attn_kernel(const unsigned* __restrict__ Qb, const unsigned* __restrict__ Kb,
                 const unsigned* __restrict__ Vb, float* __restrict__ out)
{
  __shared__ float cmb[2][64][4];                 // 2 KB

  const int bh    = blockIdx.x & 63;
  const int g     = blockIdx.x >> 6;              // 0..63
  const int w     = threadIdx.x >> 6;
  const int lane  = threadIdx.x & 63;
  const int laneq = lane & 15;
  const int quad  = lane >> 4;
  const int L = g, H = 127 - g;
  const int mL = (L + 1) >> 1, mH = (H + 1) >> 1;
  const int d   = laneq & 7;
  const bool is8 = (laneq == 8);

  const uint4* Kg = (const uint4*)Kb + (size_t)bh * 2048;
  const uint4* Qg = (const uint4*)Qb + (size_t)bh * 2048;
  const unsigned short* Vtbh = (const unsigned short*)Vb + (size_t)bh * SEQ * HDIM;

  // Q B-frags: lanes<16 hold the 8-dim row in quad 0 (k=0..7); zero others
  U16x8 qfl, qfh;
  {
    const uint4 rl = Qg[16 * L + laneq];
    const uint4 rh = Qg[16 * H + laneq];
    qfl.u = (lane < 16) ? rl : make_uint4(0u, 0u, 0u, 0u);
    qfh.u = (lane < 16) ? rh : make_uint4(0u, 0u, 0u, 0u);
  }

  float4v accL = {0.f, 0.f, 0.f, 0.f};
  float4v accH = {0.f, 0.f, 0.f, 0.f};

  if (w == 0) {
    // k-tiles [0,mL) dual (L+H), [mL,mH) H-only; no diags; prefetch 1 deep
    U16x8 kf; kf.u = Kg[laneq];
    short4v vf = load_vfrag(Vtbh, 0, quad, d, is8);
    #pragma unroll 2
    for (int t = 0; t < mH; ++t) {
      U16x8 kn; kn.u = Kg[16 * (t + 1) + laneq];  // t+1 <= mH <= 64: in-bounds
      short4v vn = load_vfrag(Vtbh, t + 1, quad, d, is8);
      if (t < mL) accL = attn_step<false>(kf.s, qfl.s, vf, accL, laneq, quad);
      accH = attn_step<false>(kf.s, qfh.s, vf, accH, laneq, quad);
      kf = kn; vf = vn;
    }
  } else {
    // L segment: [mL, L], diag at L
    U16x8 kf; kf.u = Kg[16 * mL + laneq];
    short4v vf = load_vfrag(Vtbh, mL, quad, d, is8);
    #pragma unroll 2
    for (int t = mL; t < L; ++t) {
      U16x8 kn; kn.u = Kg[16 * (t + 1) + laneq];
      short4v vn = load_vfrag(Vtbh, t + 1, quad, d, is8);
      accL = attn_step<false>(kf.s, qfl.s, vf, accL, laneq, quad);
      kf = kn; vf = vn;
    }
    accL = attn_step<true>(kf.s, qfl.s, vf, accL, laneq, quad);
    // H segment: [mH, H], diag at H
    kf.u = Kg[16 * mH + laneq];
    vf = load_vfrag(Vtbh, mH, quad, d, is8);
    #pragma unroll 2
    for (int t = mH; t < H; ++t) {
      U16x8 kn; kn.u = Kg[16 * (t + 1) + laneq];  // t+1 <= H = 127: in-bounds
      short4v vn = load_vfrag(Vtbh, t + 1, quad, d, is8);
      accH = attn_step<false>(kf.s, qfh.s, vf, accH, laneq, quad);
      kf = kn; vf = vn;
    }
    accH = attn_step<true>(kf.s, qfh.s, vf, accH, laneq, quad);

    *(float4*)&cmb[0][lane][0] = make_float4(accL[0], accL[1], accL[2], accL[3]);
    *(float4*)&cmb[1][lane][0] = make_float4(accH[0], accH[1], accH[2], accH[3]);
  }
  __syncthreads();

  if (w == 0) {
    const float4 pL = *(const float4*)&cmb[0][lane][0];
    const float4 pH = *(const float4*)&cmb[1][lane][0];
    accL[0] += pL.x; accL[1] += pL.y; accL[2] += pL.z; accL[3] += pL.w;
    accH[0] += pH.x; accH[1] += pH.y; accH[2] += pH.z; accH[3] += pH.w;
    epilogue(accL, L, bh, laneq, quad, out);
    epilogue(accH, H, bh, laneq, quad, out);
  }
}

// ---------------------------------------------------------------------------
extern "C" void kernel_launch(void* const* d_in, const int* in_sizes, int n_in,
                              void* d_out, int out_size, void* d_ws, size_t ws_size,
                              hipStream_t stream)
{
  const float* x  = (const float*)d_in[0];
  const float* Wq = (const float*)d_in[1];
  const float* bq = (const float*)d_in[2];
  const float* Wk = (const float*)d_in[3];
  const float* bk = (const float*)d_in[4];
  const float* Wv = (const float*)d_in[5];
  const float* bv = (const float*)d_in[6];
  const float* Wo = (const float*)d_in[7];
  const float* bo = (const float*)d_in[8];

  float* ws = (float*)d_ws;
  // layout: Wb 65536 u16 (in old 65536-float region) | attn 1048576 f |
  //         Qb, Kb, Vt 524288 dwords each
  unsigned short* Wb = (unsigned short*)ws;
  float*    attn = ws + 65536;
  unsigned* Qb   = (unsigned*)(ws + 65536 + 1048576);
  unsigned* Kb   = Qb + (size_t)524288;
  unsigned* Vb   = Kb + (size_t)524288;

  cast4_kernel<<<dim3(16, 4), 256, 0, stream>>>(Wq, Wk, Wv, Wo, Wb);
  qkv_kernel<<<dim3(NROW / 16, 3), 256, 0, stream>>>(x, Wb, bq, bk, bv, Qb, Kb, Vb);
  attn_kernel<<<dim3(4096), 128, 0, stream>>>(Qb, Kb, Vb, attn);
  oproj_kernel<<<dim3(NROW / 16), 256, 0, stream>>>(attn, Wb + 3 * EDIM * EDIM, bo,
                                                    (float*)d_out);
}